// Round 5
// baseline (416.638 us; speedup 1.0000x reference)
//
#include <hip/hip_runtime.h>
#include <hip/hip_bf16.h>
#include <math.h>

#define D_MODEL 512
#define N_HEADS 8
#define HEAD_DIM 64
#define BATCH 2
#define SEQ 4096
#define M_ROWS (BATCH*SEQ)   // 8192

typedef __attribute__((ext_vector_type(8))) short short8;
typedef __attribute__((ext_vector_type(4))) float f32x4;

__device__ inline short f2bf(float f) {
  union { float f; unsigned u; } v; v.f = f;
  unsigned u = v.u;
  unsigned r = u + 0x7FFFu + ((u >> 16) & 1u);
  return (short)(r >> 16);
}
__device__ inline float bf2f(short s) {
  union { unsigned u; float f; } v; v.u = ((unsigned)(unsigned short)s) << 16;
  return v.f;
}

__device__ inline void gll16(const void* g, void* l) {
  __builtin_amdgcn_global_load_lds(
      (const __attribute__((address_space(1))) unsigned int*)g,
      (__attribute__((address_space(3))) unsigned int*)l, 16, 0, 0);
}

// ---------------- prep: casts + rope tables ----------------
__global__ void prep_kernel(const float* __restrict__ x,
                            const float* __restrict__ Wq,
                            const float* __restrict__ Wk,
                            const float* __restrict__ Wv,
                            const float* __restrict__ Wo,
                            short* __restrict__ xb,
                            short* __restrict__ Wqkv,
                            short* __restrict__ Wob,
                            float* __restrict__ cosT,
                            float* __restrict__ sinT) {
  int i = blockIdx.x * blockDim.x + threadIdx.x;
  if (i < M_ROWS * D_MODEL) xb[i] = f2bf(x[i]);
  if (i < 3 * D_MODEL * D_MODEL) {
    int t = i >> 18;
    int r = i & 262143;
    const float* W = (t == 0) ? Wq : ((t == 1) ? Wk : Wv);
    Wqkv[i] = f2bf(W[r]);
  }
  if (i < D_MODEL * D_MODEL) Wob[i] = f2bf(Wo[i]);
  if (i < SEQ * 32) {
    int s = i >> 5, p = i & 31;
    float e = (float)(2 * p) * (1.0f / 64.0f);
    float inv = powf(10000.0f, -e);
    float ang = (float)s * inv;
    float sv, cv;
    sincosf(ang, &sv, &cv);
    cosT[i] = cv; sinT[i] = sv;
  }
}

// ---------------- GEMM with fused RoPE epilogue on Q/K ----------------
// MODE 0: N=1536 fused QKV; epilogue applies RoPE to Q,K (Q also scaled by
//         0.125*log2e) and scatters bf16 into Q/K [BH][S][64], Vt [BH][64][S]
// MODE 1: N=512 -> fp32 d_out
template<int MODE>
__global__ __launch_bounds__(256) void gemm_kernel(const short* __restrict__ A,
                                                   const short* __restrict__ B,
                                                   float* __restrict__ out_f,
                                                   short* __restrict__ Qb,
                                                   short* __restrict__ Kb,
                                                   short* __restrict__ Vb,
                                                   const float* __restrict__ cosT,
                                                   const float* __restrict__ sinT) {
  __shared__ short As[128][72];
  __shared__ short Bs[128][72];
  const int m0 = blockIdx.x * 128;
  const int n0 = blockIdx.y * 128;
  const int tid = threadIdx.x;
  const int lane = tid & 63, wid = tid >> 6;
  const int wm = wid >> 1, wn = wid & 1;
  const int l15 = lane & 15, g = lane >> 4;
  const int Kdim = 512;

  f32x4 acc[4][4] = {};

  for (int kt = 0; kt < Kdim; kt += 64) {
    __syncthreads();
    for (int it = 0; it < 4; ++it) {
      int c = it * 256 + tid;
      int row = c >> 3, col = (c & 7) << 3;
      *(short8*)&As[row][col] = *(const short8*)&A[(m0 + row) * Kdim + kt + col];
      *(short8*)&Bs[row][col] = *(const short8*)&B[(n0 + row) * Kdim + kt + col];
    }
    __syncthreads();
    for (int kk = 0; kk < 64; kk += 32) {
      short8 a[4], b[4];
      for (int mi = 0; mi < 4; ++mi)
        a[mi] = *(const short8*)&As[wm * 64 + mi * 16 + l15][kk + (g << 3)];
      for (int ni = 0; ni < 4; ++ni)
        b[ni] = *(const short8*)&Bs[wn * 64 + ni * 16 + l15][kk + (g << 3)];
      for (int mi = 0; mi < 4; ++mi)
        for (int ni = 0; ni < 4; ++ni)
          acc[mi][ni] = __builtin_amdgcn_mfma_f32_16x16x32_bf16(a[mi], b[ni], acc[mi][ni], 0, 0, 0);
    }
  }

  const int t_blk = (MODE == 0) ? ((n0) >> 9) : 0;  // uniform per block
  for (int mi = 0; mi < 4; ++mi)
    for (int ni = 0; ni < 4; ++ni)
      for (int r = 0; r < 4; ++r) {
        int row_g = m0 + wm * 64 + mi * 16 + (g << 2) + r;
        int col_g = n0 + wn * 64 + ni * 16 + l15;
        float v = acc[mi][ni][r];
        if (MODE == 1) {
          out_f[row_g * 512 + col_g] = v;
        } else {
          int cc = col_g & 511;
          int h = cc >> 6, d = cc & 63;
          int bb = row_g >> 12, ss = row_g & 4095;
          if (t_blk < 2) {
            // fused RoPE: pairs (even d, odd d) are adjacent lanes
            int p = d >> 1;
            float c = cosT[ss * 32 + p], sn = sinT[ss * 32 + p];
            float partner = __shfl_xor(v, 1);
            float res = (d & 1) ? (v * c + partner * sn) : (v * c - partner * sn);
            if (t_blk == 0) res *= 0.18033688011112042f;  // 0.125 * log2(e)
            short* dst = (t_blk == 0) ? Qb : Kb;
            dst[(((bb << 3) + h) * SEQ + ss) * 64 + d] = f2bf(res);
          } else {
            Vb[((((bb << 3) + h) * 64 + d)) * (long)SEQ + ss] = f2bf(v);
          }
        }
      }
}

// ---------------- flash attention (causal), LDS-staged + 2-phase ----------------
// Q,K: bf16 [BH=16][S=4096][64] (Q pre-scaled by 0.125*log2e)
// Vt:  bf16 [BH=16][64][S=4096]
// O:   bf16 [B*S=8192][512] (col = h*64+d)
// Grid 512: block o -> bh = o&15 (pins head to one XCD), tile (128 q-rows):
//   o<256: tile=31-((o&255)>>4)  (long tiles dispatched first)
//   o>=256: tile=(o&255)>>4      (complement; CU pair sums to 66 chunk-iters)
__global__ __launch_bounds__(512, 4) void attn_kernel(const short* __restrict__ Q,
                                                      const short* __restrict__ K,
                                                      const short* __restrict__ Vt,
                                                      short* __restrict__ O) {
  __shared__ short Ks[2][64 * 64];
  __shared__ short Vs[2][64 * 64];
  __shared__ short P_lds[8][16][72];

  const int o = blockIdx.x;
  const int j = (o & 255) >> 4;
  const int tile = (o < 256) ? (31 - j) : j;
  const int bh = o & 15;

  const int tid = threadIdx.x, lane = tid & 63, w = tid >> 6;
  const int l15 = lane & 15, g = lane >> 4;
  const long base = (long)bh * SEQ * 64;
  const long baseV = (long)bh * 64 * SEQ;
  const int bb = bh >> 3, h = bh & 7;

  // staging source addresses (thread-fixed parts)
  const int srow = tid >> 3;                      // 0..63
  const int sc16k = (tid & 7) ^ (srow & 7);       // swizzled 16B-block column
  short* ldsSegK0 = &Ks[0][(tid >> 6) << 9];      // wave-uniform 1KB segment
  short* ldsSegK1 = &Ks[1][(tid >> 6) << 9];
  short* ldsSegV0 = &Vs[0][(tid >> 6) << 9];
  short* ldsSegV1 = &Vs[1][(tid >> 6) << 9];

  const int q0 = (tile << 7) + (w << 4);
  const int nc = 2 * tile + 2;

  short8 aq0 = *(const short8*)&Q[base + (long)(q0 + l15) * 64 + (g << 3)];
  short8 aq1 = *(const short8*)&Q[base + (long)(q0 + l15) * 64 + 32 + (g << 3)];

  f32x4 o_acc[4] = {};
  float m_r[4], l_r[4];
#pragma unroll
  for (int r = 0; r < 4; ++r) { m_r[r] = -__builtin_inff(); l_r[r] = 0.f; }

  // prologue: stage chunk 0 -> buf 0
  gll16(&K[base + (long)srow * 64 + sc16k * 8], ldsSegK0);
  gll16(&Vt[baseV + (long)srow * SEQ + sc16k * 8], ldsSegV0);

  for (int c = 0; c < nc; ++c) {
    const int kv0 = c << 6;
    const int bi = c & 1;
    __syncthreads();   // stage(c) complete + prev reads of other buffer done
    if (c + 1 < nc) {  // stage chunk c+1 into the other buffer
      const int nkv = (c + 1) << 6;
      short* dK = (bi ? ldsSegK0 : ldsSegK1);
      short* dV = (bi ? ldsSegV0 : ldsSegV1);
      gll16(&K[base + (long)(nkv + srow) * 64 + sc16k * 8], dK);
      gll16(&Vt[baseV + (long)srow * SEQ + nkv + sc16k * 8], dV);
    }
    if (kv0 > q0) continue;   // fully-masked chunk for this wave

    // ---- QK^T from LDS (swizzled reads) ----
    f32x4 sf[4] = {};
#pragma unroll
    for (int f = 0; f < 4; ++f) {
      int row = f * 16 + l15, sw = row & 7;
      short8 bk0 = *(const short8*)&Ks[bi][row * 64 + ((g) ^ sw) * 8];
      short8 bk1 = *(const short8*)&Ks[bi][row * 64 + ((4 + g) ^ sw) * 8];
      sf[f] = __builtin_amdgcn_mfma_f32_16x16x32_bf16(aq0, bk0, sf[f], 0, 0, 0);
      sf[f] = __builtin_amdgcn_mfma_f32_16x16x32_bf16(aq1, bk1, sf[f], 0, 0, 0);
    }
    if (kv0 == (q0 & ~63)) {   // diagonal chunk: causal mask
#pragma unroll
      for (int f = 0; f < 4; ++f) {
        int kvc = kv0 + f * 16 + l15;
#pragma unroll
        for (int r = 0; r < 4; ++r) {
          int qrow = q0 + (g << 2) + r;
          if (kvc > qrow) sf[f][r] = -__builtin_inff();
        }
      }
    }

    // ---- online softmax ----
    float pm[4];
#pragma unroll
    for (int r = 0; r < 4; ++r)
      pm[r] = fmaxf(fmaxf(sf[0][r], sf[1][r]), fmaxf(sf[2][r], sf[3][r]));
#pragma unroll
    for (int off = 1; off < 16; off <<= 1)
#pragma unroll
      for (int r = 0; r < 4; ++r)
        pm[r] = fmaxf(pm[r], __shfl_xor(pm[r], off));

    float pr[4][4], rs[4];
#pragma unroll
    for (int r = 0; r < 4; ++r) {
      float mn = fmaxf(m_r[r], pm[r]);
      float alpha = exp2f(m_r[r] - mn);
      m_r[r] = mn;
      l_r[r] *= alpha;
      float s0 = 0.f;
#pragma unroll
      for (int f = 0; f < 4; ++f) {
        float pv = exp2f(sf[f][r] - mn);
        pr[f][r] = pv;
        s0 += pv;
      }
      rs[r] = s0;
#pragma unroll
      for (int db = 0; db < 4; ++db) o_acc[db][r] *= alpha;
    }
#pragma unroll
    for (int off = 1; off < 16; off <<= 1)
#pragma unroll
      for (int r = 0; r < 4; ++r)
        rs[r] += __shfl_xor(rs[r], off);
#pragma unroll
    for (int r = 0; r < 4; ++r) l_r[r] += rs[r];

    // ---- P -> LDS -> A-fragment ----
#pragma unroll
    for (int f = 0; f < 4; ++f)
#pragma unroll
      for (int r = 0; r < 4; ++r)
        P_lds[w][(g << 2) + r][f * 16 + l15] = f2bf(pr[f][r]);

    short8 pa0 = *(const short8*)&P_lds[w][l15][(g << 3)];
    short8 pa1 = *(const short8*)&P_lds[w][l15][32 + (g << 3)];

    // ---- PV from LDS (swizzled reads) ----
#pragma unroll
    for (int kk = 0; kk < 2; ++kk) {
      short8 pa = kk ? pa1 : pa0;
#pragma unroll
      for (int db = 0; db < 4; ++db) {
        int row = db * 16 + l15, sw = row & 7;
        short8 bv = *(const short8*)&Vs[bi][row * 64 + ((kk * 4 + g) ^ sw) * 8];
        o_acc[db] = __builtin_amdgcn_mfma_f32_16x16x32_bf16(pa, bv, o_acc[db], 0, 0, 0);
      }
    }
  }

  // ---- epilogue: write O ----
#pragma unroll
  for (int db = 0; db < 4; ++db)
#pragma unroll
    for (int r = 0; r < 4; ++r) {
      int s_g = q0 + (g << 2) + r;
      float v = o_acc[db][r] / l_r[r];
      O[((long)(bb * SEQ + s_g)) * 512 + h * 64 + db * 16 + l15] = f2bf(v);
    }
}

extern "C" void kernel_launch(void* const* d_in, const int* in_sizes, int n_in,
                              void* d_out, int out_size, void* d_ws, size_t ws_size,
                              hipStream_t stream) {
  const float* x  = (const float*)d_in[0];
  const float* Wq = (const float*)d_in[1];
  const float* Wk = (const float*)d_in[2];
  const float* Wv = (const float*)d_in[3];
  const float* Wo = (const float*)d_in[4];

  char* ws = (char*)d_ws;
  size_t off = 0;
  auto alloc = [&](size_t bytes) {
    void* p = ws + off;
    off += (bytes + 255) & ~(size_t)255;
    return p;
  };
  short* xb   = (short*)alloc((size_t)M_ROWS * 512 * 2);
  short* Wqkv = (short*)alloc((size_t)1536 * 512 * 2);
  short* Wob  = (short*)alloc((size_t)512 * 512 * 2);
  float* cosT = (float*)alloc((size_t)SEQ * 32 * 4);
  float* sinT = (float*)alloc((size_t)SEQ * 32 * 4);
  short* Qb   = (short*)alloc((size_t)16 * SEQ * 64 * 2);
  short* Kb   = (short*)alloc((size_t)16 * SEQ * 64 * 2);
  short* Vt   = (short*)alloc((size_t)16 * SEQ * 64 * 2);
  short* Obuf = (short*)alloc((size_t)M_ROWS * 512 * 2);

  prep_kernel<<<16384, 256, 0, stream>>>(x, Wq, Wk, Wv, Wo, xb, Wqkv, Wob, cosT, sinT);
  gemm_kernel<0><<<dim3(64, 12), 256, 0, stream>>>(xb, Wqkv, nullptr, Qb, Kb, Vt, cosT, sinT);
  attn_kernel<<<512, 512, 0, stream>>>(Qb, Kb, Vt, Obuf);
  gemm_kernel<1><<<dim3(64, 4), 256, 0, stream>>>(Obuf, Wob, (float*)d_out, nullptr, nullptr, nullptr, nullptr, nullptr);
}

// Round 6
// 246.775 us; speedup vs baseline: 1.6883x; 1.6883x over previous
//
#include <hip/hip_runtime.h>
#include <hip/hip_bf16.h>
#include <math.h>

#define D_MODEL 512
#define N_HEADS 8
#define HEAD_DIM 64
#define BATCH 2
#define SEQ 4096
#define M_ROWS (BATCH*SEQ)   // 8192

typedef __attribute__((ext_vector_type(8))) short short8;
typedef __attribute__((ext_vector_type(4))) float f32x4;

__device__ inline short f2bf(float f) {
  union { float f; unsigned u; } v; v.f = f;
  unsigned u = v.u;
  unsigned r = u + 0x7FFFu + ((u >> 16) & 1u);
  return (short)(r >> 16);
}
__device__ inline float bf2f(short s) {
  union { unsigned u; float f; } v; v.u = ((unsigned)(unsigned short)s) << 16;
  return v.f;
}

__device__ inline void gll16(const void* g, void* l) {
  __builtin_amdgcn_global_load_lds(
      (const __attribute__((address_space(1))) unsigned int*)g,
      (__attribute__((address_space(3))) unsigned int*)l, 16, 0, 0);
}

// ---------------- prep: casts + rope tables ----------------
__global__ void prep_kernel(const float* __restrict__ x,
                            const float* __restrict__ Wq,
                            const float* __restrict__ Wk,
                            const float* __restrict__ Wv,
                            const float* __restrict__ Wo,
                            short* __restrict__ xb,
                            short* __restrict__ Wqkv,
                            short* __restrict__ Wob,
                            float* __restrict__ cosT,
                            float* __restrict__ sinT) {
  int i = blockIdx.x * blockDim.x + threadIdx.x;
  if (i < M_ROWS * D_MODEL) xb[i] = f2bf(x[i]);
  if (i < 3 * D_MODEL * D_MODEL) {
    int t = i >> 18;
    int r = i & 262143;
    const float* W = (t == 0) ? Wq : ((t == 1) ? Wk : Wv);
    Wqkv[i] = f2bf(W[r]);
  }
  if (i < D_MODEL * D_MODEL) Wob[i] = f2bf(Wo[i]);
  if (i < SEQ * 32) {
    int s = i >> 5, p = i & 31;
    float e = (float)(2 * p) * (1.0f / 64.0f);
    float inv = powf(10000.0f, -e);
    float ang = (float)s * inv;
    float sv, cv;
    sincosf(ang, &sv, &cv);
    cosT[i] = cv; sinT[i] = sv;
  }
}

// ---------------- GEMM with LDS-coalesced epilogue ----------------
// MODE 0: N=1536 fused QKV; epilogue routes the 128x128 tile through LDS,
//         applies RoPE to Q/K in-register (pairs are adjacent in LDS rows),
//         writes Q/K [BH][S][64] and Vt [BH][64][S] with 16B coalesced stores.
// MODE 1: N=512 -> fp32 d_out (direct store, already line-coalesced)
template<int MODE>
__global__ __launch_bounds__(256) void gemm_kernel(const short* __restrict__ A,
                                                   const short* __restrict__ B,
                                                   float* __restrict__ out_f,
                                                   short* __restrict__ Qb,
                                                   short* __restrict__ Kb,
                                                   short* __restrict__ Vb,
                                                   const float* __restrict__ cosT,
                                                   const float* __restrict__ sinT) {
  __shared__ short smem[128 * 72 * 2];           // 36864 B, reused by epilogue
  short (*As)[72] = (short(*)[72])smem;
  short (*Bs)[72] = (short(*)[72])(smem + 128 * 72);
  short (*Cs)[136] = (short(*)[136])smem;        // 17408 shorts <= 18432*2

  const int m0 = blockIdx.x * 128;
  const int n0 = blockIdx.y * 128;
  const int tid = threadIdx.x;
  const int lane = tid & 63, wid = tid >> 6;
  const int wm = wid >> 1, wn = wid & 1;
  const int l15 = lane & 15, g = lane >> 4;
  const int Kdim = 512;

  f32x4 acc[4][4] = {};

  for (int kt = 0; kt < Kdim; kt += 64) {
    __syncthreads();
    for (int it = 0; it < 4; ++it) {
      int c = it * 256 + tid;
      int row = c >> 3, col = (c & 7) << 3;
      *(short8*)&As[row][col] = *(const short8*)&A[(m0 + row) * Kdim + kt + col];
      *(short8*)&Bs[row][col] = *(const short8*)&B[(n0 + row) * Kdim + kt + col];
    }
    __syncthreads();
    for (int kk = 0; kk < 64; kk += 32) {
      short8 a[4], b[4];
      for (int mi = 0; mi < 4; ++mi)
        a[mi] = *(const short8*)&As[wm * 64 + mi * 16 + l15][kk + (g << 3)];
      for (int ni = 0; ni < 4; ++ni)
        b[ni] = *(const short8*)&Bs[wn * 64 + ni * 16 + l15][kk + (g << 3)];
      for (int mi = 0; mi < 4; ++mi)
        for (int ni = 0; ni < 4; ++ni)
          acc[mi][ni] = __builtin_amdgcn_mfma_f32_16x16x32_bf16(a[mi], b[ni], acc[mi][ni], 0, 0, 0);
    }
  }

  if (MODE == 1) {
    for (int mi = 0; mi < 4; ++mi)
      for (int ni = 0; ni < 4; ++ni)
        for (int r = 0; r < 4; ++r) {
          int row_g = m0 + wm * 64 + mi * 16 + (g << 2) + r;
          int col_g = n0 + wn * 64 + ni * 16 + l15;
          out_f[row_g * 512 + col_g] = acc[mi][ni][r];
        }
    return;
  }

  // ---- MODE 0 epilogue: acc -> LDS (bf16) -> coalesced stores ----
  __syncthreads();   // main loop's As/Bs reads done before overwrite
  for (int mi = 0; mi < 4; ++mi)
    for (int ni = 0; ni < 4; ++ni)
      for (int r = 0; r < 4; ++r)
        Cs[wm * 64 + mi * 16 + (g << 2) + r][wn * 64 + ni * 16 + l15] =
            f2bf(acc[mi][ni][r]);
  __syncthreads();

  const int t_blk = n0 >> 9;   // 0:Q 1:K 2:V (uniform per block)
  if (t_blk < 2) {
    short* dst = (t_blk == 0) ? Qb : Kb;
    const float qs = (t_blk == 0) ? 0.18033688011112042f : 1.0f;  // 0.125*log2e
#pragma unroll
    for (int it = 0; it < 8; ++it) {
      int row = (tid >> 4) + (it << 4);           // 0..127
      int colb = (tid & 15) << 3;                 // 0..120 (8 cols)
      short8 vv = *(const short8*)&Cs[row][colb];
      int row_g = m0 + row;
      int ss = row_g & 4095, bb = row_g >> 12;
      int cc = (n0 + colb) & 511;
      int h = cc >> 6, d = cc & 63;               // d multiple of 8
      int p0 = d >> 1;                            // 4 consecutive pairs
      float4 cv = *(const float4*)&cosT[ss * 32 + p0];
      float4 sv = *(const float4*)&sinT[ss * 32 + p0];
      short8 o8;
#pragma unroll
      for (int pp = 0; pp < 4; ++pp) {
        float xe = bf2f(vv[2 * pp]), xo = bf2f(vv[2 * pp + 1]);
        float c = ((const float*)&cv)[pp], s = ((const float*)&sv)[pp];
        o8[2 * pp]     = f2bf((xe * c - xo * s) * qs);
        o8[2 * pp + 1] = f2bf((xe * s + xo * c) * qs);
      }
      *(short8*)&dst[(((bb << 3) + h) * SEQ + ss) * 64 + d] = o8;
    }
  } else {
#pragma unroll
    for (int it = 0; it < 8; ++it) {
      int c = tid & 127;                               // output d-col
      int sb = ((tid >> 7) << 3) + (it << 4);          // ss block of 8
      short8 o8;
#pragma unroll
      for (int j = 0; j < 8; ++j) o8[j] = Cs[sb + j][c];
      int row_g0 = m0 + sb;
      int ss = row_g0 & 4095, bb = row_g0 >> 12;
      int cc = (n0 + c) & 511;
      int h = cc >> 6, d = cc & 63;
      *(short8*)&Vb[((long)(((bb << 3) + h) * 64 + d)) * SEQ + ss] = o8;
    }
  }
}

// ---------------- flash attention (causal), LDS-staged + 2-phase ----------------
// (exact round-4 structure: grid 256, 8 waves, two paired 128-row tiles,
//  uniform 66 chunk-iters per block — measured 150 us)
__global__ __launch_bounds__(512, 2) void attn_kernel(const short* __restrict__ Q,
                                                      const short* __restrict__ K,
                                                      const short* __restrict__ Vt,
                                                      short* __restrict__ O) {
  __shared__ short Ks[2][64 * 64];
  __shared__ short Vs[2][64 * 64];
  __shared__ short P_lds[8][16][72];

  const int lb = blockIdx.x;                      // 0..255
  const int bh = ((lb & 7) << 1) + ((lb >> 3) & 1);  // XCD k hosts bh {2k,2k+1}
  const int pr_ = lb >> 4;                        // 0..15
  const int tA = 16 + pr_, tB = 15 - pr_;

  const int tid = threadIdx.x, lane = tid & 63, w = tid >> 6;
  const int l15 = lane & 15, g = lane >> 4;
  const long base = (long)bh * SEQ * 64;
  const long baseV = (long)bh * 64 * SEQ;
  const int bb = bh >> 3, h = bh & 7;

  const int srow = tid >> 3;                      // 0..63
  const int sc16k = (tid & 7) ^ (srow & 7);       // swizzled 16B-block column
  short* ldsSegK0 = &Ks[0][(tid >> 6) << 9];
  short* ldsSegK1 = &Ks[1][(tid >> 6) << 9];
  short* ldsSegV0 = &Vs[0][(tid >> 6) << 9];
  short* ldsSegV1 = &Vs[1][(tid >> 6) << 9];

#pragma unroll
  for (int ti = 0; ti < 2; ++ti) {
    const int tile = ti ? tB : tA;
    const int q0 = (tile << 7) + (w << 4);
    const int nc = 2 * tile + 2;

    short8 aq0 = *(const short8*)&Q[base + (long)(q0 + l15) * 64 + (g << 3)];
    short8 aq1 = *(const short8*)&Q[base + (long)(q0 + l15) * 64 + 32 + (g << 3)];

    f32x4 o_acc[4] = {};
    float m_r[4], l_r[4];
#pragma unroll
    for (int r = 0; r < 4; ++r) { m_r[r] = -__builtin_inff(); l_r[r] = 0.f; }

    __syncthreads();
    gll16(&K[base + (long)srow * 64 + sc16k * 8], ldsSegK0);
    gll16(&Vt[baseV + (long)srow * SEQ + sc16k * 8], ldsSegV0);

    for (int c = 0; c < nc; ++c) {
      const int kv0 = c << 6;
      const int bi = c & 1;
      __syncthreads();
      if (c + 1 < nc) {
        const int nkv = (c + 1) << 6;
        short* dK = (bi ? ldsSegK0 : ldsSegK1);
        short* dV = (bi ? ldsSegV0 : ldsSegV1);
        gll16(&K[base + (long)(nkv + srow) * 64 + sc16k * 8], dK);
        gll16(&Vt[baseV + (long)srow * SEQ + nkv + sc16k * 8], dV);
      }
      if (kv0 > q0) continue;

      f32x4 sf[4] = {};
#pragma unroll
      for (int f = 0; f < 4; ++f) {
        int row = f * 16 + l15, sw = row & 7;
        short8 bk0 = *(const short8*)&Ks[bi][row * 64 + ((g) ^ sw) * 8];
        short8 bk1 = *(const short8*)&Ks[bi][row * 64 + ((4 + g) ^ sw) * 8];
        sf[f] = __builtin_amdgcn_mfma_f32_16x16x32_bf16(aq0, bk0, sf[f], 0, 0, 0);
        sf[f] = __builtin_amdgcn_mfma_f32_16x16x32_bf16(aq1, bk1, sf[f], 0, 0, 0);
      }
      if (kv0 == (q0 & ~63)) {
#pragma unroll
        for (int f = 0; f < 4; ++f) {
          int kvc = kv0 + f * 16 + l15;
#pragma unroll
          for (int r = 0; r < 4; ++r) {
            int qrow = q0 + (g << 2) + r;
            if (kvc > qrow) sf[f][r] = -__builtin_inff();
          }
        }
      }

      float pm[4];
#pragma unroll
      for (int r = 0; r < 4; ++r)
        pm[r] = fmaxf(fmaxf(sf[0][r], sf[1][r]), fmaxf(sf[2][r], sf[3][r]));
#pragma unroll
      for (int off = 1; off < 16; off <<= 1)
#pragma unroll
        for (int r = 0; r < 4; ++r)
          pm[r] = fmaxf(pm[r], __shfl_xor(pm[r], off));

      float pr[4][4], rs[4];
#pragma unroll
      for (int r = 0; r < 4; ++r) {
        float mn = fmaxf(m_r[r], pm[r]);
        float alpha = exp2f(m_r[r] - mn);
        m_r[r] = mn;
        l_r[r] *= alpha;
        float s0 = 0.f;
#pragma unroll
        for (int f = 0; f < 4; ++f) {
          float pv = exp2f(sf[f][r] - mn);
          pr[f][r] = pv;
          s0 += pv;
        }
        rs[r] = s0;
#pragma unroll
        for (int db = 0; db < 4; ++db) o_acc[db][r] *= alpha;
      }
#pragma unroll
      for (int off = 1; off < 16; off <<= 1)
#pragma unroll
        for (int r = 0; r < 4; ++r)
          rs[r] += __shfl_xor(rs[r], off);
#pragma unroll
      for (int r = 0; r < 4; ++r) l_r[r] += rs[r];

#pragma unroll
      for (int f = 0; f < 4; ++f)
#pragma unroll
        for (int r = 0; r < 4; ++r)
          P_lds[w][(g << 2) + r][f * 16 + l15] = f2bf(pr[f][r]);

      short8 pa0 = *(const short8*)&P_lds[w][l15][(g << 3)];
      short8 pa1 = *(const short8*)&P_lds[w][l15][32 + (g << 3)];

#pragma unroll
      for (int kk = 0; kk < 2; ++kk) {
        short8 pa = kk ? pa1 : pa0;
#pragma unroll
        for (int db = 0; db < 4; ++db) {
          int row = db * 16 + l15, sw = row & 7;
          short8 bv = *(const short8*)&Vs[bi][row * 64 + ((kk * 4 + g) ^ sw) * 8];
          o_acc[db] = __builtin_amdgcn_mfma_f32_16x16x32_bf16(pa, bv, o_acc[db], 0, 0, 0);
        }
      }
    }

#pragma unroll
    for (int db = 0; db < 4; ++db)
#pragma unroll
      for (int r = 0; r < 4; ++r) {
        int s_g = q0 + (g << 2) + r;
        float v = o_acc[db][r] / l_r[r];
        O[((long)(bb * SEQ + s_g)) * 512 + h * 64 + db * 16 + l15] = f2bf(v);
      }
  }
}

extern "C" void kernel_launch(void* const* d_in, const int* in_sizes, int n_in,
                              void* d_out, int out_size, void* d_ws, size_t ws_size,
                              hipStream_t stream) {
  const float* x  = (const float*)d_in[0];
  const float* Wq = (const float*)d_in[1];
  const float* Wk = (const float*)d_in[2];
  const float* Wv = (const float*)d_in[3];
  const float* Wo = (const float*)d_in[4];

  char* ws = (char*)d_ws;
  size_t off = 0;
  auto alloc = [&](size_t bytes) {
    void* p = ws + off;
    off += (bytes + 255) & ~(size_t)255;
    return p;
  };
  short* xb   = (short*)alloc((size_t)M_ROWS * 512 * 2);
  short* Wqkv = (short*)alloc((size_t)1536 * 512 * 2);
  short* Wob  = (short*)alloc((size_t)512 * 512 * 2);
  float* cosT = (float*)alloc((size_t)SEQ * 32 * 4);
  float* sinT = (float*)alloc((size_t)SEQ * 32 * 4);
  short* Qb   = (short*)alloc((size_t)16 * SEQ * 64 * 2);
  short* Kb   = (short*)alloc((size_t)16 * SEQ * 64 * 2);
  short* Vt   = (short*)alloc((size_t)16 * SEQ * 64 * 2);
  short* Obuf = (short*)alloc((size_t)M_ROWS * 512 * 2);

  prep_kernel<<<16384, 256, 0, stream>>>(x, Wq, Wk, Wv, Wo, xb, Wqkv, Wob, cosT, sinT);
  gemm_kernel<0><<<dim3(64, 12), 256, 0, stream>>>(xb, Wqkv, nullptr, Qb, Kb, Vt, cosT, sinT);
  attn_kernel<<<256, 512, 0, stream>>>(Qb, Kb, Vt, Obuf);
  gemm_kernel<1><<<dim3(64, 4), 256, 0, stream>>>(Obuf, Wob, (float*)d_out, nullptr, nullptr, nullptr, nullptr, nullptr);
}